// Round 4
// baseline (611.003 us; speedup 1.0000x reference)
//
#include <hip/hip_runtime.h>
#include <stdint.h>

#define NQ 10000
#define NC 2048
#define NW 157           // ceil(10000/64)
#define IOU_TH 0.5f

// -------- ws layout (bytes) --------
// scores : [0,       40000)
// rank   : [40000,   80000)
// boxes4 : [80000,  240000)   10000*4 f32 (xyxy, clipped+scaled)
// sx1    : [240000, 280000)   sorted SoA
// sy1    : [280000, 320000)
// sx2    : [320000, 360000)
// sy2    : [360000, 400000)
// sarea  : [400000, 440000)
// order  : [440000, 480000)   sorted index -> original index
// mask   : [480000, 480000+10000*157*8 = 13,040,000)

__global__ __launch_bounds__(256) void k_scores(const float* __restrict__ logits,
        float* __restrict__ out_scores, float* __restrict__ out_labels,
        float* __restrict__ ws_scores) {
    int wave = threadIdx.x >> 6;
    int lane = threadIdx.x & 63;
    int q = blockIdx.x * 4 + wave;
    if (q >= NQ) return;
    const float* row = logits + (size_t)q * NC;
    float4 v[8];
    float m = -3.4e38f;
    int am = 0;
    #pragma unroll
    for (int k = 0; k < 8; k++) {
        int idx = k * 256 + lane * 4;
        v[k] = *(const float4*)(row + idx);
        // strict > keeps first occurrence within this lane's ascending indices
        if (v[k].x > m) { m = v[k].x; am = idx; }
        if (v[k].y > m) { m = v[k].y; am = idx + 1; }
        if (v[k].z > m) { m = v[k].z; am = idx + 2; }
        if (v[k].w > m) { m = v[k].w; am = idx + 3; }
    }
    #pragma unroll
    for (int off = 32; off >= 1; off >>= 1) {
        float om = __shfl_xor(m, off);
        int   oa = __shfl_xor(am, off);
        if (om > m || (om == m && oa < am)) { m = om; am = oa; }
    }
    float s = 0.f;
    #pragma unroll
    for (int k = 0; k < 8; k++) {
        s += expf(v[k].x - m);
        s += expf(v[k].y - m);
        s += expf(v[k].z - m);
        s += expf(v[k].w - m);
    }
    #pragma unroll
    for (int off = 32; off >= 1; off >>= 1) s += __shfl_xor(s, off);
    if (lane == 0) {
        float sc = 1.0f / s;           // max prob = exp(0)/sum = 1/sum
        out_scores[q] = sc;
        out_labels[q] = (float)am;
        ws_scores[q]  = sc;
    }
}

__global__ __launch_bounds__(256) void k_cls(const float* __restrict__ cls,
                                             float* __restrict__ out) {
    float m = -3.4e38f; int am = 0x7fffffff;
    for (int idx = threadIdx.x; idx < NC; idx += 256) {
        float x = cls[idx];
        if (x > m) { m = x; am = idx; }    // per-thread indices ascending
    }
    int lane = threadIdx.x & 63, wave = threadIdx.x >> 6;
    #pragma unroll
    for (int off = 32; off >= 1; off >>= 1) {
        float om = __shfl_xor(m, off); int oa = __shfl_xor(am, off);
        if (om > m || (om == m && oa < am)) { m = om; am = oa; }
    }
    __shared__ float sm[4]; __shared__ int sa[4];
    if (lane == 0) { sm[wave] = m; sa[wave] = am; }
    __syncthreads();
    if (threadIdx.x == 0) {
        for (int w = 1; w < 4; w++)
            if (sm[w] > m || (sm[w] == m && sa[w] < am)) { m = sm[w]; am = sa[w]; }
        out[0] = (float)am;
    }
}

__global__ __launch_bounds__(256) void k_boxes(const float* __restrict__ pb,
        const int* __restrict__ ts, float* __restrict__ out_boxes,
        float* __restrict__ boxes4, int* __restrict__ rank) {
    #pragma clang fp contract(off)
    int i = blockIdx.x * 256 + threadIdx.x;
    if (i >= NQ) return;
    rank[i] = 0;
    // target_sizes may be int64 (low/high word pairs) or int32; values in [480,1333)
    int a0 = ts[0], a1 = ts[1];
    int ih, iw;
    if (a1 == 0) { ih = a0; iw = ts[2]; } else { ih = a0; iw = a1; }
    float sh = (float)ih, sw = (float)iw;
    float4 b = *(const float4*)(pb + i * 4);
    float x1 = b.x - 0.5f * b.z;
    float y1 = b.y - 0.5f * b.w;
    float x2 = b.x + 0.5f * b.z;
    float y2 = b.y + 0.5f * b.w;
    x1 = fminf(fmaxf(x1, 0.f), 1.f) * sw;
    y1 = fminf(fmaxf(y1, 0.f), 1.f) * sh;
    x2 = fminf(fmaxf(x2, 0.f), 1.f) * sw;
    y2 = fminf(fmaxf(y2, 0.f), 1.f) * sh;
    float4 o = make_float4(x1, y1, x2, y2);
    *(float4*)(out_boxes + i * 4) = o;
    *(float4*)(boxes4 + i * 4) = o;
}

// rank[i] = #{j: s_j > s_i} + #{j: s_j == s_i && j < i}  == position in argsort(-s) (stable)
__global__ __launch_bounds__(256) void k_count(const float* __restrict__ scores,
                                               int* __restrict__ rank) {
    __shared__ float sc[2000];
    int jbase = blockIdx.y * 2000;
    int jn = min(2000, NQ - jbase);
    for (int t = threadIdx.x; t < jn; t += 256) sc[t] = scores[jbase + t];
    __syncthreads();
    int i = blockIdx.x * 256 + threadIdx.x;
    if (i >= NQ) return;
    float si = scores[i];
    int cnt = 0;
    for (int jj = 0; jj < jn; jj++) {
        float sj = sc[jj];
        int j = jbase + jj;
        cnt += (sj > si) || (sj == si && j < i);
    }
    if (cnt) atomicAdd(&rank[i], cnt);
}

__global__ __launch_bounds__(256) void k_scatter(const float* __restrict__ boxes4,
        const int* __restrict__ rank, int* __restrict__ order,
        float* __restrict__ sx1, float* __restrict__ sy1,
        float* __restrict__ sx2, float* __restrict__ sy2,
        float* __restrict__ sarea) {
    #pragma clang fp contract(off)
    int i = blockIdx.x * 256 + threadIdx.x;
    if (i >= NQ) return;
    int r = rank[i];
    order[r] = i;
    float4 b = *(const float4*)(boxes4 + i * 4);
    sx1[r] = b.x; sy1[r] = b.y; sx2[r] = b.z; sy2[r] = b.w;
    sarea[r] = fmaxf(b.z - b.x, 0.f) * fmaxf(b.w - b.y, 0.f);
}

// mask[i][cb] bit jj = (j>i) && IoU(i, j)>0.5, j = cb*64+jj (sorted order)
__global__ __launch_bounds__(64) void k_mask(const float* __restrict__ sx1,
        const float* __restrict__ sy1, const float* __restrict__ sx2,
        const float* __restrict__ sy2, const float* __restrict__ sarea,
        unsigned long long* __restrict__ mask) {
    #pragma clang fp contract(off)
    int rb = blockIdx.x, cb = blockIdx.y;
    if (cb < rb) return;
    int t = threadIdx.x;
    __shared__ float cx1[64], cy1[64], cx2[64], cy2[64], ca[64];
    int j0 = cb * 64 + t;
    if (j0 < NQ) { cx1[t]=sx1[j0]; cy1[t]=sy1[j0]; cx2[t]=sx2[j0]; cy2[t]=sy2[j0]; ca[t]=sarea[j0]; }
    __syncthreads();
    int i = rb * 64 + t;
    if (i >= NQ) return;
    float xi1 = sx1[i], yi1 = sy1[i], xi2 = sx2[i], yi2 = sy2[i], ai = sarea[i];
    int ncol = min(64, NQ - cb * 64);
    unsigned long long word = 0;
    for (int jj = 0; jj < ncol; jj++) {
        int j = cb * 64 + jj;
        float lx = fmaxf(xi1, cx1[jj]);
        float ly = fmaxf(yi1, cy1[jj]);
        float rx = fminf(xi2, cx2[jj]);
        float ry = fminf(yi2, cy2[jj]);
        float w = fmaxf(rx - lx, 0.f);
        float h = fmaxf(ry - ly, 0.f);
        float inter = w * h;
        float denom = (ai + ca[jj]) - inter;   // ref op order: (areas[i]+areas)-inter
        float iou = inter / denom;
        bool sup = (iou > IOU_TH) && (j > i);
        word |= ((unsigned long long)(sup ? 1u : 0u)) << jj;
    }
    mask[(size_t)i * NW + cb] = word;
}

// Single-wave sequential greedy reduce.
// - "removed" bitmap in VGPRs: word w held by lane (w & 63), slot (w >> 6).
// - Resolve loop is fully SCALAR (SGPRs + v_readlane).
// - Row-suffix ORs: 16 rows x 3 slots = 48 independent loads issued as
//   EXPLICIT NAMED REGISTERS (no arrays -> no scratch), one latency exposure.
//   Dummy slots load row c*64 (always valid) and are masked with 0.
__global__ __launch_bounds__(64) void k_scan(const unsigned long long* __restrict__ mask,
        const int* __restrict__ order, float* __restrict__ out_keep) {
    int lane = threadIdx.x & 63;
    uint64_t r0 = 0, r1 = 0, r2 = 0;     // removed words: lane, lane+64, lane+128
    const int w0 = lane, w1 = lane + 64, w2 = lane + 128;
    const bool w2v = (w2 < NW);
    const int w2s = w2v ? w2 : 0;        // always-in-bounds slot-2 index

    // prefetch chunk 0's diag word + order
    uint32_t dg_lo, dg_hi;
    {
        uint64_t dg = mask[(size_t)lane * NW + 0];
        dg_lo = (uint32_t)dg; dg_hi = (uint32_t)(dg >> 32);
    }
    int ord = order[lane];

    for (int c = 0; c < NW; c++) {
        const int c64 = c * 64;

        // ---- prefetch next chunk (k_mask outputs, never mutated) ----
        uint64_t dg_n = 0; int ord_n = 0;
        if (c + 1 < NW) {
            int i2 = c64 + 64 + lane;
            if (i2 < NQ) {
                dg_n  = mask[(size_t)i2 * NW + (c + 1)];
                ord_n = order[i2];
            }
        }

        // ---- removed-in word for this chunk (scalar via readlane) ----
        int cl = c & 63;
        uint32_t rlo, rhi;
        if (c < 64) {
            rlo = __builtin_amdgcn_readlane((uint32_t)r0, cl);
            rhi = __builtin_amdgcn_readlane((uint32_t)(r0 >> 32), cl);
        } else if (c < 128) {
            rlo = __builtin_amdgcn_readlane((uint32_t)r1, cl);
            rhi = __builtin_amdgcn_readlane((uint32_t)(r1 >> 32), cl);
        } else {
            rlo = __builtin_amdgcn_readlane((uint32_t)r2, cl);
            rhi = __builtin_amdgcn_readlane((uint32_t)(r2 >> 32), cl);
        }
        uint64_t cur = ((uint64_t)rhi << 32) | rlo;
        int nvalid = min(64, NQ - c64);
        if (nvalid < 64) cur |= (~0ull) << nvalid;   // invalid tail = suppressed

        // ---- scalar greedy resolve over alive bits ----
        uint64_t alive = ~cur;
        uint64_t kept = 0;
        while (alive) {
            int b = (int)__builtin_ctzll(alive);
            uint32_t dlo = __builtin_amdgcn_readlane(dg_lo, b);
            uint32_t dhi = __builtin_amdgcn_readlane(dg_hi, b);
            uint64_t d = ((uint64_t)dhi << 32) | dlo;   // row b's diag word (bits > b only)
            kept  |= 1ull << b;
            cur   |= d;
            alive &= ~(d | (1ull << b));
        }

        // ---- write keep for this chunk (before loads: ack overlaps load latency) ----
        if (c64 + lane < NQ) out_keep[ord] = ((cur >> lane) & 1ull) ? 0.f : 1.f;

        // ---- OR kept rows' suffix words into the register bitmap ----
        uint64_t kmr = kept;
        while (kmr) {
#define NMS_PICK(t) \
            int b##t; uint64_t m##t; \
            if (kmr) { b##t = (int)__builtin_ctzll(kmr); kmr &= kmr - 1; m##t = ~0ull; } \
            else     { b##t = 0; m##t = 0ull; }
            NMS_PICK(0)  NMS_PICK(1)  NMS_PICK(2)  NMS_PICK(3)
            NMS_PICK(4)  NMS_PICK(5)  NMS_PICK(6)  NMS_PICK(7)
            NMS_PICK(8)  NMS_PICK(9)  NMS_PICK(10) NMS_PICK(11)
            NMS_PICK(12) NMS_PICK(13) NMS_PICK(14) NMS_PICK(15)
#undef NMS_PICK

#define NMS_LOAD(t) \
            const unsigned long long* p##t = mask + (size_t)(c64 + b##t) * NW; \
            uint64_t a##t##_0 = p##t[w0]; \
            uint64_t a##t##_1 = p##t[w1]; \
            uint64_t a##t##_2 = p##t[w2s];
            NMS_LOAD(0)  NMS_LOAD(1)  NMS_LOAD(2)  NMS_LOAD(3)
            NMS_LOAD(4)  NMS_LOAD(5)  NMS_LOAD(6)  NMS_LOAD(7)
            NMS_LOAD(8)  NMS_LOAD(9)  NMS_LOAD(10) NMS_LOAD(11)
            NMS_LOAD(12) NMS_LOAD(13) NMS_LOAD(14) NMS_LOAD(15)
#undef NMS_LOAD

            uint64_t s0 = (a0_0 & m0) | (a1_0 & m1) | (a2_0 & m2) | (a3_0 & m3)
                        | (a4_0 & m4) | (a5_0 & m5) | (a6_0 & m6) | (a7_0 & m7)
                        | (a8_0 & m8) | (a9_0 & m9) | (a10_0 & m10) | (a11_0 & m11)
                        | (a12_0 & m12) | (a13_0 & m13) | (a14_0 & m14) | (a15_0 & m15);
            uint64_t s1 = (a0_1 & m0) | (a1_1 & m1) | (a2_1 & m2) | (a3_1 & m3)
                        | (a4_1 & m4) | (a5_1 & m5) | (a6_1 & m6) | (a7_1 & m7)
                        | (a8_1 & m8) | (a9_1 & m9) | (a10_1 & m10) | (a11_1 & m11)
                        | (a12_1 & m12) | (a13_1 & m13) | (a14_1 & m14) | (a15_1 & m15);
            uint64_t s2 = (a0_2 & m0) | (a1_2 & m1) | (a2_2 & m2) | (a3_2 & m3)
                        | (a4_2 & m4) | (a5_2 & m5) | (a6_2 & m6) | (a7_2 & m7)
                        | (a8_2 & m8) | (a9_2 & m9) | (a10_2 & m10) | (a11_2 & m11)
                        | (a12_2 & m12) | (a13_2 & m13) | (a14_2 & m14) | (a15_2 & m15);

            if (w0 > c)         r0 |= s0;
            if (w1 > c)         r1 |= s1;
            if (w2v && w2 > c)  r2 |= s2;
        }

        dg_lo = (uint32_t)dg_n; dg_hi = (uint32_t)(dg_n >> 32); ord = ord_n;
    }
}

extern "C" void kernel_launch(void* const* d_in, const int* in_sizes, int n_in,
                              void* d_out, int out_size, void* d_ws, size_t ws_size,
                              hipStream_t stream) {
    const float* pred_logits = (const float*)d_in[0];
    const float* pred_boxes  = (const float*)d_in[1];
    const float* cls_logits  = (const float*)d_in[2];
    const int*   tsizes      = (const int*)d_in[3];

    float* out = (float*)d_out;
    float* out_scores = out;
    float* out_labels = out + 10000;
    float* out_boxes  = out + 20000;
    float* out_keep   = out + 60000;
    float* out_cls    = out + 70000;

    char* ws = (char*)d_ws;
    float* ws_scores = (float*)(ws + 0);
    int*   rank      = (int*)  (ws + 40000);
    float* boxes4    = (float*)(ws + 80000);
    float* sx1       = (float*)(ws + 240000);
    float* sy1       = (float*)(ws + 280000);
    float* sx2       = (float*)(ws + 320000);
    float* sy2       = (float*)(ws + 360000);
    float* sarea     = (float*)(ws + 400000);
    int*   order     = (int*)  (ws + 440000);
    unsigned long long* mask = (unsigned long long*)(ws + 480000);

    k_scores<<<2500, 256, 0, stream>>>(pred_logits, out_scores, out_labels, ws_scores);
    k_cls<<<1, 256, 0, stream>>>(cls_logits, out_cls);
    k_boxes<<<40, 256, 0, stream>>>(pred_boxes, tsizes, out_boxes, boxes4, rank);
    k_count<<<dim3(40, 5), 256, 0, stream>>>(ws_scores, rank);
    k_scatter<<<40, 256, 0, stream>>>(boxes4, rank, order, sx1, sy1, sx2, sy2, sarea);
    k_mask<<<dim3(157, 157), 64, 0, stream>>>(sx1, sy1, sx2, sy2, sarea, mask);
    k_scan<<<1, 64, 0, stream>>>(mask, order, out_keep);
}